// Round 5
// baseline (51.228 us; speedup 1.0000x reference)
//
#include <hip/hip_runtime.h>
#include <hip/hip_bf16.h>

typedef __attribute__((ext_vector_type(4))) float f32x4;
typedef __attribute__((ext_vector_type(8))) short short8;

#define B_ 16
#define C_ 64
#define H_ 128
#define W_ 128
#define Z_ 128
#define IDXN (C_*C_*9)    // 36864 weight elements per sample
#define NT 18             // K=576 -> 18 MFMA k-steps of 32

__device__ __forceinline__ unsigned short f2bf(float f) {
  __hip_bfloat16 h = __float2bfloat16(f);
  return *reinterpret_cast<unsigned short*>(&h);
}

// ---------------- kernel 1: weight generation, pre-swizzled to MFMA fragment layout
__global__ __launch_bounds__(256) void wgen_k(
    const float* __restrict__ z, const float* __restrict__ gw,
    const float* __restrict__ gb, unsigned short* __restrict__ wfrag) {
  __shared__ __align__(16) float zs[B_*Z_];   // 8 KB
  int t = threadIdx.x;
#pragma unroll
  for (int i = 0; i < 8; ++i) zs[i*256 + t] = z[i*256 + t];
  __syncthreads();
  int lane = t & 63, bg = t >> 6;
  int b0 = bg*4;
  int idx0 = blockIdx.x*128 + lane;           // stream 0: idx0, stream 1: idx0+64
  float acc[4][2];
  float bv0 = gb[idx0], bv1 = gb[idx0 + 64];
#pragma unroll
  for (int bi = 0; bi < 4; ++bi) { acc[bi][0] = bv0; acc[bi][1] = bv1; }

  for (int z0 = 0; z0 < Z_; z0 += 4) {
    float ga[4], gbv[4];
#pragma unroll
    for (int zi = 0; zi < 4; ++zi) {
      ga[zi]  = gw[(size_t)(z0+zi)*IDXN + idx0];
      gbv[zi] = gw[(size_t)(z0+zi)*IDXN + idx0 + 64];
    }
#pragma unroll
    for (int bi = 0; bi < 4; ++bi) {
      f32x4 zq = *reinterpret_cast<const f32x4*>(&zs[(b0+bi)*Z_ + z0]);
      acc[bi][0] = fmaf(zq[0], ga[0], fmaf(zq[1], ga[1], fmaf(zq[2], ga[2], fmaf(zq[3], ga[3], acc[bi][0]))));
      acc[bi][1] = fmaf(zq[0], gbv[0], fmaf(zq[1], gbv[1], fmaf(zq[2], gbv[2], fmaf(zq[3], gbv[3], acc[bi][1]))));
    }
  }
#pragma unroll
  for (int ni = 0; ni < 2; ++ni) {
    int idx = idx0 + ni*64;
    int kw = idx % 3, r1 = idx/3;
    int kh = r1 % 3, r2 = r1/3;
    int ci = r2 & 63, co = r2 >> 6;
    int k = (kh*3 + kw)*C_ + ci;
    int ts = k >> 5, kin = k & 31;
    int lm = (co & 15) | ((kin >> 3) << 4);
    int j = kin & 7, m = co >> 4;
    int base = ((ts*4 + m)*64 + lm)*8 + j;
#pragma unroll
    for (int bi = 0; bi < 4; ++bi)
      wfrag[(size_t)(b0+bi)*(NT*4*64*8) + base] = f2bf(acc[bi][ni]);
  }
}

// ---------------- kernel 2 (fused): per-sample conv as MFMA implicit GEMM
// 512 threads = 8 waves; wave v: row phr=v>>2, px half pw0=((v>>1)&1)*64, co half cb=(v&1)*32
// LDS: xs[4 rows][130 cols][8 chunk-slots][16B]; slot s at col holds chunk s^(col&7)
__global__ __launch_bounds__(512, 4) void conv_k(
    const float* __restrict__ x,
    const unsigned short* __restrict__ wfrag,
    float* __restrict__ out) {
  __shared__ __align__(16) unsigned char xs[4*130*128];   // 66560 B -> 2 blocks/CU, 16 waves
  int orig = blockIdx.x;
  int blk = (orig & 7)*128 + (orig >> 3);   // bijective XCD swizzle: 1024 = 8*128
  int b = blk >> 6;
  int h0 = (blk & 63)*2;
  int tid = threadIdx.x;
  int v = tid >> 6, lane = tid & 63;

  // ---- stage 4 halo rows (h0-1..h0+2); wave v stages (row v>>1, chunk-half v&1)
  {
    int r = v >> 1, hf = v & 1;
    int hh = h0 - 1 + r;
    bool hv = (hh >= 0) & (hh < H_);
    unsigned char* ldsrow = xs + r*(130*128);
    if (hv) {
      if (lane < 8) {   // zero pad col 0 (hf=0) / col 129 (hf=1)
        int s = hf ? (1032 + lane) : lane;
        uint4 zv; zv.x = 0; zv.y = 0; zv.z = 0; zv.w = 0;
        *reinterpret_cast<uint4*>(ldsrow + s*16) = zv;
      }
      const float* xrow = x + (((size_t)b*C_)*H_ + hh)*W_;   // + ci*(H_*W_) + w
      int w0 = 2*lane, col0 = w0 + 1, col1 = w0 + 2;
      int g = lane >> 3;                                     // chunk rotation
#pragma unroll
      for (int i = 0; i < 4; ++i) {
        int chunk = (hf*4 + i + g) & 7;
        float2 v2[8];
#pragma unroll
        for (int j = 0; j < 8; ++j)
          v2[j] = *reinterpret_cast<const float2*>(xrow + (size_t)(chunk*8 + j)*(H_*W_) + w0);
        uint4 o0, o1;
        unsigned short* s0 = reinterpret_cast<unsigned short*>(&o0);
        unsigned short* s1 = reinterpret_cast<unsigned short*>(&o1);
#pragma unroll
        for (int j = 0; j < 8; ++j) {
          s0[j] = f2bf(v2[j].x);
          s1[j] = f2bf(v2[j].y);
        }
        int a0 = col0*128 + (((chunk ^ col0) & 7) << 4);
        int a1 = col1*128 + (((chunk ^ col1) & 7) << 4);
        *reinterpret_cast<uint4*>(ldsrow + a0) = o0;
        *reinterpret_cast<uint4*>(ldsrow + a1) = o1;
      }
    } else {
      uint4 zv; zv.x = 0; zv.y = 0; zv.z = 0; zv.w = 0;
#pragma unroll
      for (int it = 0; it < 9; ++it) {   // zero half the row: 520 slots each
        int di = it*64 + lane;
        if (di < 520) *reinterpret_cast<uint4*>(ldsrow + (hf*520 + di)*16) = zv;
      }
    }
  }

  int l15 = lane & 15, lhi = lane >> 4;
  int phr = v >> 2, pw0 = ((v >> 1) & 1)*64;
  int mt0 = (v & 1)*2;                       // co-tile base (co = mt0*16 .. +31)
  const unsigned short* wb = wfrag + (size_t)b*(NT*4*64*8);

  // prefetch t=0 weight tiles above the barrier (VGPR-dest, no LDS dep)
  short8 wf0 = *reinterpret_cast<const short8*>(wb + (((0*4 + mt0 + 0)*64 + lane)*8));
  short8 wf1 = *reinterpret_cast<const short8*>(wb + (((0*4 + mt0 + 1)*64 + lane)*8));

  __syncthreads();

  f32x4 acc[4][2];   // [pixel tile][co tile]
#pragma unroll
  for (int mp = 0; mp < 4; ++mp)
#pragma unroll
    for (int nc = 0; nc < 2; ++nc)
      acc[mp][nc] = (f32x4){0.f, 0.f, 0.f, 0.f};

#pragma unroll
  for (int t = 0; t < NT; ++t) {
    int kk = t >> 1, kh = kk/3, kw = kk%3, half = t & 1;
    short8 nf0, nf1;
    if (t + 1 < NT) {                        // prefetch next weight tiles
      nf0 = *reinterpret_cast<const short8*>(wb + ((((t+1)*4 + mt0 + 0)*64 + lane)*8));
      nf1 = *reinterpret_cast<const short8*>(wb + ((((t+1)*4 + mt0 + 1)*64 + lane)*8));
    }
    int chunk = half*4 + lhi;                // ci0>>3
    short8 xa[4];
#pragma unroll
    for (int mp = 0; mp < 4; ++mp) {         // A operand: pixels from LDS
      int col = pw0 + mp*16 + l15 + kw;      // padded col = pix + kw, in [0,129]
      int addr = ((phr + kh)*130 + col)*128 + (((chunk ^ col) & 7) << 4);
      xa[mp] = *reinterpret_cast<const short8*>(&xs[addr]);
    }
#pragma unroll
    for (int mp = 0; mp < 4; ++mp) {
      acc[mp][0] = __builtin_amdgcn_mfma_f32_16x16x32_bf16(xa[mp], wf0, acc[mp][0], 0, 0, 0);
      acc[mp][1] = __builtin_amdgcn_mfma_f32_16x16x32_bf16(xa[mp], wf1, acc[mp][1], 0, 0, 0);
    }
    wf0 = nf0; wf1 = nf1;
  }

  // ---- epilogue: D row=(lane>>4)*4+i -> pixel (contiguous f32x4), col=lane&15 -> co
  int ph = h0 + phr;
#pragma unroll
  for (int nc = 0; nc < 2; ++nc) {
    int co = (mt0 + nc)*16 + l15;
    float* op = out + (((size_t)b*C_ + co)*H_ + ph)*W_;
#pragma unroll
    for (int mp = 0; mp < 4; ++mp) {
      int pix = pw0 + mp*16 + lhi*4;
      *reinterpret_cast<f32x4*>(op + pix) = acc[mp][nc];
    }
  }
}

__global__ void sentinel_k(float* out, int n) {
  int i = blockIdx.x*256 + threadIdx.x;
  if (i < n) out[i] = 1.0e6f;
}

extern "C" void kernel_launch(void* const* d_in, const int* in_sizes, int n_in,
                              void* d_out, int out_size, void* d_ws, size_t ws_size,
                              hipStream_t stream) {
  const float* x  = (const float*)d_in[0];
  const float* z  = (const float*)d_in[1];
  const float* gw = (const float*)d_in[2];
  const float* gb = (const float*)d_in[3];
  float* out = (float*)d_out;

  size_t wfrag_elems = (size_t)B_*IDXN;                   // bf16 elems
  size_t need = wfrag_elems*sizeof(unsigned short);
  if (ws_size < need) {
    sentinel_k<<<(out_size + 255)/256, 256, 0, stream>>>(out, out_size);
    return;
  }
  unsigned short* wfrag = (unsigned short*)d_ws;

  wgen_k <<<IDXN/128, 256, 0, stream>>>(z, gw, gb, wfrag);
  conv_k <<<B_*(H_/2), 512, 0, stream>>>(x, wfrag, out);
}